// Round 2
// baseline (87.835 us; speedup 1.0000x reference)
//
#include <hip/hip_runtime.h>
#include <math.h>

// RBF kernel matrix: cov[i][j] = exp(lv - 0.5*||(x_i - xx_j) * inv_scale||^2)
// Expanded form (all in log2 domain so v_exp_f32 applies directly):
//   W[d]    = inv_scale[d]^2 * log2(e)
//   B[j,d]  = xx[j,d] * W[d]
//   c[j]    = lv*log2(e) - 0.5 * sum_d xx[j,d]^2 * W[d]
//   h_i     = -0.5 * sum_d x[i,d]^2 * W[d]
//   cov     = exp2(h_i + c_j + sum_d x[i,d] * B[j,d])
// Per output: 8 FMA + 1 add + 1 v_exp_f32. Write-BW floor: 67 MB / 5.9 TB/s
// (proven by harness fill kernels) ~= 11.4 us.
// R2: TJ 4->8 as two stride-1024 column groups (keeps each wave store
// 1KB-contiguous), exp2 folding. Halves wave count, -20% VALU per output.

constexpr int D   = 8;   // feature dim (fixed by reference)
constexpr int TJG = 4;   // columns per group -> one float4 store
constexpr int NG  = 2;   // column groups per thread
constexpr int TI  = 8;   // rows per block
constexpr int BLK = 256; // threads per block

typedef float f32x4 __attribute__((ext_vector_type(4)));

__global__ __launch_bounds__(BLK) void rbf_kernel(
    const float* __restrict__ x,         // [N, D]
    const float* __restrict__ xx,        // [M, D]
    const float* __restrict__ log_scale, // [D]
    const float* __restrict__ log_var,   // [1]
    float* __restrict__ out,             // [N, M]
    int N, int M)
{
    const int tid     = threadIdx.x;
    const int colspan = BLK * TJG;                       // 1024 cols per group
    const int jbase   = blockIdx.x * (colspan * NG) + tid * TJG;
    const int i0      = blockIdx.y * TI;
    if (jbase + (NG - 1) * colspan + TJG > M || i0 + TI > N) return;

    constexpr float LOG2E = 1.4426950408889634f;
    float w[D];
#pragma unroll
    for (int d = 0; d < D; ++d) {
        const float s = __expf(-log_scale[d]);  // 1/scale
        w[d] = s * s * LOG2E;                   // log2e folded in
    }
    const float lv2 = log_var[0] * LOG2E;

    // Per-column precompute (registers): B[g][jj][d], c[g][jj]
    float B[NG][TJG][D], c[NG][TJG];
#pragma unroll
    for (int g = 0; g < NG; ++g) {
#pragma unroll
        for (int jj = 0; jj < TJG; ++jj) {
            const int j = jbase + g * colspan + jj;
            const float4* p = (const float4*)(xx + (size_t)j * D);
            const float4 a = p[0], b = p[1];
            const float v[D] = {a.x, a.y, a.z, a.w, b.x, b.y, b.z, b.w};
            float q = 0.f;
#pragma unroll
            for (int d = 0; d < D; ++d) {
                B[g][jj][d] = v[d] * w[d];
                q = fmaf(v[d], B[g][jj][d], q);  // sum xx^2 * W
            }
            c[g][jj] = fmaf(-0.5f, q, lv2);
        }
    }

#pragma unroll
    for (int r = 0; r < TI; ++r) {
        const int i = i0 + r;
        // x-row address is wave-uniform -> broadcast fetch, L1/L2-hot.
        const float4* px = (const float4*)(x + (size_t)i * D);
        const float4 a = px[0], b = px[1];
        const float v[D] = {a.x, a.y, a.z, a.w, b.x, b.y, b.z, b.w};
        float q = 0.f;
#pragma unroll
        for (int d = 0; d < D; ++d) q = fmaf(v[d] * w[d], v[d], q);
        const float h = -0.5f * q;

#pragma unroll
        for (int g = 0; g < NG; ++g) {
            float res[TJG];
#pragma unroll
            for (int jj = 0; jj < TJG; ++jj) {
                float e = h + c[g][jj];
#pragma unroll
                for (int d = 0; d < D; ++d) e = fmaf(v[d], B[g][jj][d], e);
                res[jj] = __builtin_amdgcn_exp2f(e);
            }
            const f32x4 o = {res[0], res[1], res[2], res[3]};
            __builtin_nontemporal_store(
                o, (f32x4*)(out + (size_t)i * M + jbase + g * colspan));
        }
    }
}

extern "C" void kernel_launch(void* const* d_in, const int* in_sizes, int n_in,
                              void* d_out, int out_size, void* d_ws, size_t ws_size,
                              hipStream_t stream) {
    const float* x  = (const float*)d_in[0];
    const float* xx = (const float*)d_in[1];
    const float* ls = (const float*)d_in[2];
    const float* lv = (const float*)d_in[3];
    float* out      = (float*)d_out;

    const int N = in_sizes[0] / D;
    const int M = in_sizes[1] / D;

    const int cols_per_block = BLK * TJG * NG;  // 2048
    dim3 block(BLK, 1, 1);
    dim3 grid((M + cols_per_block - 1) / cols_per_block, (N + TI - 1) / TI, 1);
    rbf_kernel<<<grid, block, 0, stream>>>(x, xx, ls, lv, out, N, M);
}